// Round 4
// baseline (1003.135 us; speedup 1.0000x reference)
//
#include <hip/hip_runtime.h>

#define T_STEPS 2000
#define NN 39
#define K1 2496          // 39*64, original K
#define K2 4992          // hi/lo duplicated K
#define KS 6             // K-splits in gemm1 (partial buffers, no atomics)
#define KSP 832          // K2 per split = 13 chunks of 64
#define KCHUNKS 13
#define CH_L 50
#define CH_W 50
#define NCH 40           // 40*50 = 2000
#define GRID 256
#define NSYNC 7
#define SYNC_BYTES (NSYNC * 4096)

using short8 = __attribute__((ext_vector_type(8))) short;
using floatx4 = __attribute__((ext_vector_type(4))) float;

struct Params {
    const float* x; const int* ei; const float* Wc; const float* bc;
    const float* W1; const float* b1; const float* W2; const float* b2;
    const float* W3; const float* b3; float* out;
    unsigned int* SYNC;
    float* H1; float* H2; float* H3;
    float* F1p; float* G2; float* G3; float* PART;
    unsigned int* W1t; unsigned char* FS; unsigned char* S1;
};

__device__ __forceinline__ unsigned int bf16_rne(float v) {
    unsigned int u = __float_as_uint(v);
    return (u + 0x7FFFu + ((u >> 16) & 1u)) >> 16;
}

// Leader-only grid sync: 8 spread arrival counters (RELEASE add), block-0 leader
// aggregates (ACQUIRE loads) and publishes a release flag; others spin ACQUIRE.
// Per-phase area: 1024 u32 (4 KB); counter s at [s*64], release flag at [768].
__device__ __forceinline__ void gsync(unsigned int* S, int phase) {
    __syncthreads();   // drains vmcnt: block's global stores are at least in L2
    if (threadIdx.x == 0) {
        unsigned int* area = S + phase * 1024;
        __hip_atomic_fetch_add(&area[(blockIdx.x & 7) * 64], 1u,
                               __ATOMIC_RELEASE, __HIP_MEMORY_SCOPE_AGENT);
        if (blockIdx.x == 0) {
            for (;;) {
                unsigned int tot = 0;
                #pragma unroll
                for (int s = 0; s < 8; ++s)
                    tot += __hip_atomic_load(&area[s * 64], __ATOMIC_ACQUIRE,
                                             __HIP_MEMORY_SCOPE_AGENT);
                if (tot == GRID) break;
                __builtin_amdgcn_s_sleep(2);
            }
            __hip_atomic_store(&area[768], 1u, __ATOMIC_RELEASE,
                               __HIP_MEMORY_SCOPE_AGENT);
        } else {
            while (__hip_atomic_load(&area[768], __ATOMIC_ACQUIRE,
                                     __HIP_MEMORY_SCOPE_AGENT) == 0)
                __builtin_amdgcn_s_sleep(2);
        }
    }
    __syncthreads();
}

__global__ __launch_bounds__(256) void fused(Params p) {
    __shared__ __align__(16) float smemf[6144];   // 24.5 KB, reused per phase
    const int bid = blockIdx.x, tid = threadIdx.x;

    // ============ Phase A: per-block A_hat (LDS) + 3-hop tiles + W1 bf16 prep ============
    {
        float* ah = smemf;           // A then A_hat in place, 1521
        float* xs = smemf + 1536;    // 1248
        float* hb = smemf + 2816;    // 1248
        float* dinv = smemf + 4100;  // 39
        for (int u = tid; u < NN * NN; u += 256) ah[u] = 0.0f;
        __syncthreads();
        if (tid < 156) {
            int r = p.ei[tid], c = p.ei[156 + tid];
            atomicAdd(&ah[c * NN + r], 1.0f);
        }
        __syncthreads();
        if (tid < NN) {
            float d = 0.0f;
            for (int u = 0; u < NN; ++u) d += ah[tid * NN + u];
            dinv[tid] = (d > 0.0f) ? (1.0f / sqrtf(d)) : 0.0f;
        }
        __syncthreads();
        for (int u = tid; u < NN * NN; u += 256) {
            int i = u / NN, j = u % NN;
            ah[u] = (dinv[i] * ah[u]) * dinv[j];
        }
        __syncthreads();
        // hop tile: blocks 0..124, one 16-step tile each
        if (bid < 125) {
            int t0 = bid * 16;
            for (int e = tid; e < 78 * 16; e += 256) {
                int r = e >> 4, tt = e & 15;
                xs[e] = p.x[r * T_STEPS + t0 + tt];
            }
            __syncthreads();
            for (int e = tid; e < 1248; e += 256) {
                int r = e >> 4, tt = e & 15;
                int i = r >> 1, c = r & 1;
                float acc = 0.0f;
                #pragma unroll
                for (int m = 0; m < NN; ++m)
                    acc += ah[i * NN + m] * xs[(2 * m + c) * 16 + tt];
                hb[e] = acc;
            }
            __syncthreads();
            for (int e = tid; e < 1248; e += 256) {
                int r = e >> 4, tt = e & 15;
                p.H1[r * T_STEPS + t0 + tt] = hb[e];
            }
            for (int e = tid; e < 1248; e += 256) {
                int r = e >> 4, tt = e & 15;
                int i = r >> 1, c = r & 1;
                float acc = 0.0f;
                #pragma unroll
                for (int m = 0; m < NN; ++m)
                    acc += ah[i * NN + m] * hb[(2 * m + c) * 16 + tt];
                xs[e] = acc;
            }
            __syncthreads();
            for (int e = tid; e < 1248; e += 256) {
                int r = e >> 4, tt = e & 15;
                p.H2[r * T_STEPS + t0 + tt] = xs[e];
            }
            for (int e = tid; e < 1248; e += 256) {
                int r = e >> 4, tt = e & 15;
                int i = r >> 1, c = r & 1;
                float acc = 0.0f;
                #pragma unroll
                for (int m = 0; m < NN; ++m)
                    acc += ah[i * NN + m] * xs[(2 * m + c) * 16 + tt];
                hb[e] = acc;
            }
            __syncthreads();
            for (int e = tid; e < 1248; e += 256) {
                int r = e >> 4, tt = e & 15;
                p.H3[r * T_STEPS + t0 + tt] = hb[e];
            }
        }
        // W1 -> bf16 hi/lo (strided over all blocks)
        const int total = 128 * K1;
        for (int f = bid * 256 + tid; f < total; f += GRID * 256) {
            int j = f / K1, k = f - j * K1;
            float w = p.W1[k * 128 + j];
            unsigned int hi = bf16_rne(w);
            float r = w - __uint_as_float(hi << 16);     // exact
            unsigned int lo = bf16_rne(r);
            p.W1t[j * K1 + k] = (hi & 0xFFFFu) | (lo << 16);
        }
    }
    gsync(p.SYNC, 0);

    // ============ Phase B: layer-1 scan (conv fused), 400 logical blocks =================
    for (int lb = bid; lb < 10 * NCH; lb += GRID) {
        int nb = lb % 10, chunk = lb / 10;
        int n = nb * 256 + tid;
        if (n < K1) {
            int i = n >> 6, j = n & 63;
            const float* bases[4] = {p.x, p.H1, p.H2, p.H3};
            const float* hp[8];
            float wv[8];
            #pragma unroll
            for (int k = 0; k < 4; ++k)
                #pragma unroll
                for (int c = 0; c < 2; ++c) {
                    hp[k * 2 + c] = bases[k] + (i * 2 + c) * T_STEPS;
                    wv[k * 2 + c] = p.Wc[(k * 2 + c) * 64 + j];
                }
            float bias = p.bc[j];
            int t0 = chunk * CH_L;
            int tw = t0 - CH_W; if (tw < 0) tw = 0;
            float m = 0.0f, s = 0.0f;
            for (int t = tw; t < t0; ++t) {
                float acc = 0.0f;
                #pragma unroll
                for (int q = 0; q < 8; ++q) acc += wv[q] * hp[q][t];
                float v = acc + bias;
                m = m * 0.2f * (1.0f - s) + v;
                s = (m > 0.5f) ? 1.0f : 0.0f;
            }
            for (int t = t0; t < t0 + CH_L; ++t) {
                float acc = 0.0f;
                #pragma unroll
                for (int q = 0; q < 8; ++q) acc += wv[q] * hp[q][t];
                float v = acc + bias;
                m = m * 0.2f * (1.0f - s) + v;
                s = (m > 0.5f) ? 1.0f : 0.0f;
                p.FS[t * K1 + n] = (unsigned char)(s != 0.0f);
            }
        }
    }
    gsync(p.SYNC, 1);

    // ============ Phase C: gemm1 MFMA bf16 hi/lo, 63 t-tiles x 6 K-splits ================
    {
        short* As = (short*)smemf;           // 32*72
        short* Ws = (short*)smemf + 2304;    // 128*72
        const short* W1s = (const short*)p.W1t;
        int lane = tid & 63;
        int wv = tid >> 6;
        int j0 = wv * 32;
        int row = lane & 15;
        int quad = lane >> 4;
        int sm = tid >> 3;
        int sb4 = (tid & 7) * 4;
        for (int lb = bid; lb < 63 * KS; lb += GRID) {
            int tb = lb % 63, ks = lb / 63;
            int t0 = tb * 32;
            int kb_orig = ks * 416;
            int kb2 = ks * KSP;
            floatx4 acc00 = {0.f, 0.f, 0.f, 0.f};
            floatx4 acc01 = acc00, acc10 = acc00, acc11 = acc00;
            for (int c = 0; c < KCHUNKS; ++c) {
                unsigned int u4 = 0;
                int gt = t0 + sm;
                if (gt < T_STEPS)
                    u4 = *(const unsigned int*)&p.FS[gt * K1 + kb_orig + c * 32 + sb4];
                uint4 dd;
                dd.x = (u4 & 0x000000FFu) ? 0x3F803F80u : 0u;
                dd.y = (u4 & 0x0000FF00u) ? 0x3F803F80u : 0u;
                dd.z = (u4 & 0x00FF0000u) ? 0x3F803F80u : 0u;
                dd.w = (u4 & 0xFF000000u) ? 0x3F803F80u : 0u;
                *(uint4*)&As[sm * 72 + sb4 * 2] = dd;
                #pragma unroll
                for (int u = 0; u < 4; ++u) {
                    int aid = u * 256 + tid;
                    int jj = aid >> 3;
                    int ko = (aid & 7) * 8;
                    short8 w = *(const short8*)&W1s[jj * K2 + kb2 + c * 64 + ko];
                    *(short8*)&Ws[jj * 72 + ko] = w;
                }
                __syncthreads();
                #pragma unroll
                for (int s = 0; s < 2; ++s) {
                    int k0 = s * 32 + quad * 8;
                    short8 a0 = *(const short8*)&As[row * 72 + k0];
                    short8 a1 = *(const short8*)&As[(row + 16) * 72 + k0];
                    short8 b0 = *(const short8*)&Ws[(j0 + row) * 72 + k0];
                    short8 b1 = *(const short8*)&Ws[(j0 + 16 + row) * 72 + k0];
                    acc00 = __builtin_amdgcn_mfma_f32_16x16x32_bf16(a0, b0, acc00, 0, 0, 0);
                    acc01 = __builtin_amdgcn_mfma_f32_16x16x32_bf16(a0, b1, acc01, 0, 0, 0);
                    acc10 = __builtin_amdgcn_mfma_f32_16x16x32_bf16(a1, b0, acc10, 0, 0, 0);
                    acc11 = __builtin_amdgcn_mfma_f32_16x16x32_bf16(a1, b1, acc11, 0, 0, 0);
                }
                __syncthreads();
            }
            float* outp = p.F1p + (size_t)ks * T_STEPS * 128;
            #pragma unroll
            for (int r = 0; r < 4; ++r) {
                int m0 = quad * 4 + r;
                int t = t0 + m0;
                if (t < T_STEPS) {
                    outp[t * 128 + j0 + row]      = acc00[r];
                    outp[t * 128 + j0 + 16 + row] = acc01[r];
                }
                int t2 = t0 + 16 + m0;
                if (t2 < T_STEPS) {
                    outp[t2 * 128 + j0 + row]      = acc10[r];
                    outp[t2 * 128 + j0 + 16 + row] = acc11[r];
                }
            }
        }
    }
    gsync(p.SYNC, 2);

    // ============ Phase D: h1 scan (sums 6 partials), 40 chunk-blocks ====================
    if (bid < NCH && tid < 128) {
        int n = tid;
        int t0 = bid * CH_L;
        int tw = t0 - CH_W; if (tw < 0) tw = 0;
        float b = p.b1[n];
        float m = 0.0f, s = 0.0f;
        const float* p0 = p.F1p + n;
        for (int t = tw; t < t0; ++t) {
            float v = 0.0f;
            #pragma unroll
            for (int q = 0; q < KS; ++q) v += p0[(size_t)q * T_STEPS * 128 + t * 128];
            v += b;
            m = m * 0.2f * (1.0f - s) + v;
            s = (m > 0.5f) ? 1.0f : 0.0f;
        }
        for (int t = t0; t < t0 + CH_L; ++t) {
            float v = 0.0f;
            #pragma unroll
            for (int q = 0; q < KS; ++q) v += p0[(size_t)q * T_STEPS * 128 + t * 128];
            v += b;
            m = m * 0.2f * (1.0f - s) + v;
            s = (m > 0.5f) ? 1.0f : 0.0f;
            p.S1[t * 128 + n] = (unsigned char)(s != 0.0f);
        }
    }
    gsync(p.SYNC, 3);

    // ============ Phase E: gemm2  G2[t][j] = S1[t][:] @ W2, 125 t-tiles of 16 ============
    if (bid < 125) {
        float* AT = smemf;   // [k][t] 128*16
        int t0 = bid * 16;
        {
            int t = tid >> 4, k0 = (tid & 15) * 8;
            const uchar4* q = (const uchar4*)&p.S1[(t0 + t) * 128 + k0];
            uchar4 b0 = q[0], b1v = q[1];
            AT[(k0 + 0) * 16 + t] = (float)b0.x;
            AT[(k0 + 1) * 16 + t] = (float)b0.y;
            AT[(k0 + 2) * 16 + t] = (float)b0.z;
            AT[(k0 + 3) * 16 + t] = (float)b0.w;
            AT[(k0 + 4) * 16 + t] = (float)b1v.x;
            AT[(k0 + 5) * 16 + t] = (float)b1v.y;
            AT[(k0 + 6) * 16 + t] = (float)b1v.z;
            AT[(k0 + 7) * 16 + t] = (float)b1v.w;
        }
        __syncthreads();
        int j = tid;
        float acc[16] = {0.0f};
        for (int k = 0; k < 128; ++k) {
            float w = p.W2[k * 256 + j];
            float4 a0 = *(const float4*)&AT[k * 16 + 0];
            float4 a1 = *(const float4*)&AT[k * 16 + 4];
            float4 a2 = *(const float4*)&AT[k * 16 + 8];
            float4 a3 = *(const float4*)&AT[k * 16 + 12];
            acc[0]  += a0.x * w; acc[1]  += a0.y * w; acc[2]  += a0.z * w; acc[3]  += a0.w * w;
            acc[4]  += a1.x * w; acc[5]  += a1.y * w; acc[6]  += a1.z * w; acc[7]  += a1.w * w;
            acc[8]  += a2.x * w; acc[9]  += a2.y * w; acc[10] += a2.z * w; acc[11] += a2.w * w;
            acc[12] += a3.x * w; acc[13] += a3.y * w; acc[14] += a3.z * w; acc[15] += a3.w * w;
        }
        #pragma unroll
        for (int tt = 0; tt < 16; ++tt) p.G2[(t0 + tt) * 256 + j] = acc[tt];
    }
    gsync(p.SYNC, 4);

    // ============ Phase F: h2 scan + gemm3 fused (S2 stays in LDS), 40 chunk-blocks ======
    if (bid < NCH) {
        unsigned char* s2 = (unsigned char*)smemf;   // [50][256] u8
        int n = tid;
        int t0 = bid * CH_L;
        int tw = t0 - CH_W; if (tw < 0) tw = 0;
        float b = p.b2[n];
        float m = 0.0f, s = 0.0f;
        for (int t = tw; t < t0; ++t) {
            float v = p.G2[t * 256 + n] + b;
            m = m * 0.2f * (1.0f - s) + v;
            s = (m > 0.5f) ? 1.0f : 0.0f;
        }
        for (int tl = 0; tl < CH_L; ++tl) {
            float v = p.G2[(t0 + tl) * 256 + n] + b;
            m = m * 0.2f * (1.0f - s) + v;
            s = (m > 0.5f) ? 1.0f : 0.0f;
            s2[tl * 256 + n] = (unsigned char)(s != 0.0f);
        }
        __syncthreads();
        for (int e = tid; e < CH_L * 36; e += 256) {
            int tl = e / 36, j = e - tl * 36;
            const unsigned char* srow = &s2[tl * 256];
            float acc = 0.0f;
            for (int k = 0; k < 256; k += 4) {
                uchar4 q = *(const uchar4*)&srow[k];
                acc += (float)q.x * p.W3[(k + 0) * 36 + j];
                acc += (float)q.y * p.W3[(k + 1) * 36 + j];
                acc += (float)q.z * p.W3[(k + 2) * 36 + j];
                acc += (float)q.w * p.W3[(k + 3) * 36 + j];
            }
            p.G3[(t0 + tl) * 36 + j] = acc;
        }
    }
    gsync(p.SYNC, 5);

    // ============ Phase G: h3 scan + spike counts, 40 chunk-blocks =======================
    if (bid < NCH && tid < 36) {
        int n = tid;
        int t0 = bid * CH_L;
        int tw = t0 - CH_W; if (tw < 0) tw = 0;
        float b = p.b3[n];
        float m = 0.0f, s = 0.0f;
        int cnt = 0;
        for (int t = tw; t < t0; ++t) {
            float v = p.G3[t * 36 + n] + b;
            m = m * 0.2f * (1.0f - s) + v;
            s = (m > 0.5f) ? 1.0f : 0.0f;
        }
        for (int t = t0; t < t0 + CH_L; ++t) {
            float v = p.G3[t * 36 + n] + b;
            m = m * 0.2f * (1.0f - s) + v;
            s = (m > 0.5f) ? 1.0f : 0.0f;
            cnt += (s != 0.0f) ? 1 : 0;
        }
        p.PART[bid * 36 + n] = (float)cnt;
    }
    gsync(p.SYNC, 6);

    // ============ Finalize (block 0) =====================================================
    if (bid == 0 && tid < 36) {
        float sum = 0.0f;
        for (int c = 0; c < NCH; ++c) sum += p.PART[c * 36 + tid];
        p.out[tid] = sum / 2000.0f;
    }
}

extern "C" void kernel_launch(void* const* d_in, const int* in_sizes, int n_in,
                              void* d_out, int out_size, void* d_ws, size_t ws_size,
                              hipStream_t stream) {
    Params p;
    p.x  = (const float*)d_in[0];
    p.ei = (const int*)d_in[1];
    p.Wc = (const float*)d_in[2];
    p.bc = (const float*)d_in[3];
    p.W1 = (const float*)d_in[4];
    p.b1 = (const float*)d_in[5];
    p.W2 = (const float*)d_in[6];
    p.b2 = (const float*)d_in[7];
    p.W3 = (const float*)d_in[8];
    p.b3 = (const float*)d_in[9];
    p.out = (float*)d_out;

    p.SYNC = (unsigned int*)d_ws;
    float* w = (float*)((char*)d_ws + SYNC_BYTES);
    p.H1  = w;                    w += 156000;
    p.H2  = w;                    w += 156000;
    p.H3  = w;                    w += 156000;
    p.F1p = w;                    w += (size_t)KS * T_STEPS * 128;
    p.G2  = w;                    w += (size_t)T_STEPS * 256;
    p.G3  = w;                    w += (size_t)T_STEPS * 36;
    p.PART = w;                   w += NCH * 36 + 64;
    p.W1t = (unsigned int*)w;     w += 128 * K1;
    p.FS = (unsigned char*)w;
    p.S1 = p.FS + (size_t)T_STEPS * K1;

    hipMemsetAsync(d_ws, 0, SYNC_BYTES, stream);
    void* args[] = {(void*)&p};
    hipLaunchCooperativeKernel((const void*)fused, dim3(GRID), dim3(256), args, 0, stream);
}

// Round 5
// 327.121 us; speedup vs baseline: 3.0666x; 3.0666x over previous
//
#include <hip/hip_runtime.h>

#define T 2000
#define K1N 2496         // 39*64
#define KS 6             // gemm1 K-splits (partial buffers, no atomics)
#define FSP (T * 128)    // elements per F1 partial

using short8 = __attribute__((ext_vector_type(8))) short;
using floatx4 = __attribute__((ext_vector_type(4))) float;

__device__ __forceinline__ unsigned bf16_rne(float v) {
    unsigned u = __float_as_uint(v);
    return (u + 0x7FFFu + ((u >> 16) & 1u)) >> 16;
}
__device__ __forceinline__ unsigned packhl(float w) {
    unsigned hi = bf16_rne(w);
    float r = w - __uint_as_float(hi << 16);   // exact
    unsigned lo = bf16_rne(r);
    return (hi & 0xFFFFu) | (lo << 16);
}

// ============ K1: A_hat + 3 hops (LDS ping-pong) + c1 scan -> FS ====================
// grid (10, 40): blockIdx.x = neuron group (256 neurons = 4 nodes), .y = 50-t chunk.
// Exact R2 arithmetic: hop dot order m=0..38; conv q order (x,h1,h2,h3)x(c0,c1); warm 50.
__global__ __launch_bounds__(256) void conv_scan(const float* __restrict__ x,
        const int* __restrict__ ei, const float* __restrict__ Wc,
        const float* __restrict__ bc, unsigned char* __restrict__ FS) {
    __shared__ float ah[1560];      // A_hat [39][39], dinv at 1521..1559
    __shared__ float bufA[3900];    // [78 rows][50 t]
    __shared__ float bufB[3900];
    __shared__ float own[1600];     // [4 levels][8 local rows][50 t]
    int tid = threadIdx.x;
    int nb = blockIdx.x, ch = blockIdx.y;

    for (int u = tid; u < 1521; u += 256) ah[u] = 0.f;
    __syncthreads();
    if (tid < 156) atomicAdd(&ah[ei[156 + tid] * 39 + ei[tid]], 1.f);
    __syncthreads();
    if (tid < 39) {
        float d = 0.f;
        for (int u = 0; u < 39; ++u) d += ah[tid * 39 + u];
        ah[1521 + tid] = (d > 0.f) ? (1.f / sqrtf(d)) : 0.f;
    }
    __syncthreads();
    for (int u = tid; u < 1521; u += 256) {
        int i = u / 39, j = u - i * 39;
        ah[u] = (ah[1521 + i] * ah[u]) * ah[1521 + j];
    }
    __syncthreads();

    int t0 = ch * 50;
    int n = nb * 256 + tid;
    bool vn = n < K1N;
    int i0 = nb * 4;
    int iloc = (n >> 6) - i0;
    int j = n & 63;
    float wv[8], bias = 0.f;
    #pragma unroll
    for (int q = 0; q < 8; ++q) wv[q] = 0.f;
    if (vn) {
        #pragma unroll
        for (int q = 0; q < 8; ++q) wv[q] = Wc[q * 64 + j];
        bias = bc[j];
    }
    float m = 0.f, s = 0.f;
    for (int st = 0; st < 2; ++st) {         // st=0: warm sub-tile, st=1: output sub-tile
        int ts = t0 + (st - 1) * 50;
        if (ts < 0) continue;
        for (int e = tid; e < 3900; e += 256) {
            int r = e / 50, tt = e - r * 50;
            bufA[e] = x[r * T + ts + tt];
        }
        __syncthreads();
        for (int e = tid; e < 400; e += 256) {           // own level 0 (x)
            int lr = e / 50, tt = e - lr * 50;
            int gr = i0 * 2 + lr;
            own[e] = (gr < 78) ? bufA[gr * 50 + tt] : 0.f;
        }
        for (int e = tid; e < 3900; e += 256) {          // h1 = A_hat @ x
            int r = e / 50, tt = e - r * 50;
            int ii = r >> 1, c = r & 1;
            float acc = 0.f;
            #pragma unroll
            for (int mm = 0; mm < 39; ++mm) acc += ah[ii * 39 + mm] * bufA[(2 * mm + c) * 50 + tt];
            bufB[e] = acc;
        }
        __syncthreads();
        for (int e = tid; e < 400; e += 256) {           // own level 1
            int lr = e / 50, tt = e - lr * 50;
            int gr = i0 * 2 + lr;
            own[400 + e] = (gr < 78) ? bufB[gr * 50 + tt] : 0.f;
        }
        for (int e = tid; e < 3900; e += 256) {          // h2 = A_hat @ h1
            int r = e / 50, tt = e - r * 50;
            int ii = r >> 1, c = r & 1;
            float acc = 0.f;
            #pragma unroll
            for (int mm = 0; mm < 39; ++mm) acc += ah[ii * 39 + mm] * bufB[(2 * mm + c) * 50 + tt];
            bufA[e] = acc;
        }
        __syncthreads();
        for (int e = tid; e < 400; e += 256) {           // own level 2
            int lr = e / 50, tt = e - lr * 50;
            int gr = i0 * 2 + lr;
            own[800 + e] = (gr < 78) ? bufA[gr * 50 + tt] : 0.f;
        }
        for (int e = tid; e < 400; e += 256) {           // own level 3: h3 rows for own nodes only
            int lr = e / 50, tt = e - lr * 50;
            int gi = i0 + (lr >> 1), c = lr & 1;
            float acc = 0.f;
            if (gi < 39) {
                #pragma unroll
                for (int mm = 0; mm < 39; ++mm) acc += ah[gi * 39 + mm] * bufA[(2 * mm + c) * 50 + tt];
            }
            own[1200 + e] = acc;
        }
        __syncthreads();
        if (vn) {
            int ro = iloc * 2;
            for (int tt = 0; tt < 50; ++tt) {
                float acc = 0.f;
                #pragma unroll
                for (int lv = 0; lv < 4; ++lv) {
                    acc += wv[lv * 2 + 0] * own[lv * 400 + (ro + 0) * 50 + tt];
                    acc += wv[lv * 2 + 1] * own[lv * 400 + (ro + 1) * 50 + tt];
                }
                float v = acc + bias;
                m = m * 0.2f * (1.f - s) + v;
                s = (m > 0.5f) ? 1.f : 0.f;
                if (st == 1) FS[(ts + tt) * K1N + n] = (unsigned char)(s != 0.f);
            }
        }
        __syncthreads();
    }
}

// ============ K2: gemm1 MFMA bf16 hi/lo, W1 conversion inlined into staging ==========
// grid (63, 6). F1p[ks][t][j] partial sums (no atomics). Bit-identical to R2 gemm1.
__global__ __launch_bounds__(256) void gemm1(const unsigned char* __restrict__ FS,
        const float* __restrict__ W1, float* __restrict__ F1p) {
    __shared__ short As[32 * 72];    // [m][k'] pad
    __shared__ short Ws[128 * 80];   // [j][k'] rows of 40 u32 (16B-aligned uint4 stores)
    int tid = threadIdx.x;
    int t0 = blockIdx.x * 32;
    int ks = blockIdx.y;
    int lane = tid & 63, wvi = tid >> 6;
    int j0 = wvi * 32;
    int row = lane & 15, quad = lane >> 4;
    floatx4 a00 = {0.f, 0.f, 0.f, 0.f};
    floatx4 a01 = a00, a10 = a00, a11 = a00;
    int kb = ks * 416;
    int sm = tid >> 3, sb4 = (tid & 7) * 4;
    for (int c = 0; c < 13; ++c) {
        unsigned u4 = 0;
        int gt = t0 + sm;
        if (gt < T) u4 = *(const unsigned*)&FS[gt * K1N + kb + c * 32 + sb4];
        uint4 dd;
        dd.x = (u4 & 0x000000FFu) ? 0x3F803F80u : 0u;
        dd.y = (u4 & 0x0000FF00u) ? 0x3F803F80u : 0u;
        dd.z = (u4 & 0x00FF0000u) ? 0x3F803F80u : 0u;
        dd.w = (u4 & 0xFF000000u) ? 0x3F803F80u : 0u;
        *(uint4*)&As[sm * 72 + sb4 * 2] = dd;
        #pragma unroll
        for (int u = 0; u < 4; ++u) {
            int aid = u * 256 + tid;
            int jj = aid >> 3, k4 = (aid & 7) * 4;
            int krow = kb + c * 32 + k4;
            uint4 pk;
            pk.x = packhl(W1[(krow + 0) * 128 + jj]);
            pk.y = packhl(W1[(krow + 1) * 128 + jj]);
            pk.z = packhl(W1[(krow + 2) * 128 + jj]);
            pk.w = packhl(W1[(krow + 3) * 128 + jj]);
            *(uint4*)&((unsigned*)Ws)[jj * 40 + k4] = pk;
        }
        __syncthreads();
        #pragma unroll
        for (int sh = 0; sh < 2; ++sh) {
            int k0 = sh * 32 + quad * 8;
            short8 fa0 = *(const short8*)&As[row * 72 + k0];
            short8 fa1 = *(const short8*)&As[(row + 16) * 72 + k0];
            short8 fb0 = *(const short8*)&Ws[(j0 + row) * 80 + k0];
            short8 fb1 = *(const short8*)&Ws[(j0 + 16 + row) * 80 + k0];
            a00 = __builtin_amdgcn_mfma_f32_16x16x32_bf16(fa0, fb0, a00, 0, 0, 0);
            a01 = __builtin_amdgcn_mfma_f32_16x16x32_bf16(fa0, fb1, a01, 0, 0, 0);
            a10 = __builtin_amdgcn_mfma_f32_16x16x32_bf16(fa1, fb0, a10, 0, 0, 0);
            a11 = __builtin_amdgcn_mfma_f32_16x16x32_bf16(fa1, fb1, a11, 0, 0, 0);
        }
        __syncthreads();
    }
    float* outp = F1p + (size_t)ks * FSP;
    #pragma unroll
    for (int r = 0; r < 4; ++r) {
        int m0 = quad * 4 + r;
        int t = t0 + m0;
        if (t < T) { outp[t * 128 + j0 + row] = a00[r]; outp[t * 128 + j0 + 16 + row] = a01[r]; }
        int t2 = t0 + 16 + m0;
        if (t2 < T) { outp[t2 * 128 + j0 + row] = a10[r]; outp[t2 * 128 + j0 + 16 + row] = a11[r]; }
    }
}

// ============ K3: h1 scan (warm 20, per 16-t tile) + gemm2 -> G2 =====================
// grid 125. S1 spikes written as floats directly into gemm2's AT[k][t] layout.
__global__ __launch_bounds__(256) void h1_gemm2(const float* __restrict__ F1p,
        const float* __restrict__ b1, const float* __restrict__ W2,
        float* __restrict__ G2) {
    __shared__ float AT[128 * 16];
    int tid = threadIdx.x;
    int t0 = blockIdx.x * 16;
    if (tid < 128) {
        int n = tid;
        int hs = t0 - 20; if (hs < 0) hs = 0;
        float b = b1[n];
        float m = 0.f, s = 0.f;
        const float* p0 = F1p + n;
        for (int t = hs; t < t0 + 16; ++t) {
            float v = 0.f;
            #pragma unroll
            for (int q = 0; q < KS; ++q) v += p0[(size_t)q * FSP + t * 128];
            v += b;
            m = m * 0.2f * (1.f - s) + v;
            s = (m > 0.5f) ? 1.f : 0.f;
            if (t >= t0) AT[n * 16 + (t - t0)] = s;
        }
    }
    __syncthreads();
    int j = tid;
    float acc[16] = {0.f};
    for (int k = 0; k < 128; ++k) {
        float w = W2[k * 256 + j];
        float4 q0 = *(const float4*)&AT[k * 16 + 0];
        float4 q1 = *(const float4*)&AT[k * 16 + 4];
        float4 q2 = *(const float4*)&AT[k * 16 + 8];
        float4 q3 = *(const float4*)&AT[k * 16 + 12];
        acc[0]  += q0.x * w; acc[1]  += q0.y * w; acc[2]  += q0.z * w; acc[3]  += q0.w * w;
        acc[4]  += q1.x * w; acc[5]  += q1.y * w; acc[6]  += q1.z * w; acc[7]  += q1.w * w;
        acc[8]  += q2.x * w; acc[9]  += q2.y * w; acc[10] += q2.z * w; acc[11] += q2.w * w;
        acc[12] += q3.x * w; acc[13] += q3.y * w; acc[14] += q3.z * w; acc[15] += q3.w * w;
    }
    #pragma unroll
    for (int tt = 0; tt < 16; ++tt) G2[(t0 + tt) * 256 + j] = acc[tt];
}

// ============ K4: h2 scan + gemm3 (S2 in LDS) + h3 scan + atomic out =================
// grid 40. h2 warm from t0-100 so S2/G3 cover [t0-50, t0+50) for h3's 50-warm.
__global__ __launch_bounds__(256) void tail(const float* __restrict__ G2,
        const float* __restrict__ b2, const float* __restrict__ W3,
        const float* __restrict__ b3, float* __restrict__ out) {
    __shared__ unsigned char S2[100 * 256];
    __shared__ float G3[100 * 36];
    int tid = threadIdx.x;
    int t0 = blockIdx.x * 50;
    int gs = t0 - 50; if (gs < 0) gs = 0;
    int hs = gs - 50; if (hs < 0) hs = 0;
    {
        int n = tid;
        float b = b2[n];
        float m = 0.f, s = 0.f;
        for (int t = hs; t < t0 + 50; ++t) {
            float v = G2[t * 256 + n] + b;
            m = m * 0.2f * (1.f - s) + v;
            s = (m > 0.5f) ? 1.f : 0.f;
            if (t >= gs) S2[(t - gs) * 256 + n] = (unsigned char)(s != 0.f);
        }
    }
    __syncthreads();
    int L3 = t0 + 50 - gs;
    for (int e = tid; e < L3 * 36; e += 256) {
        int tl = e / 36, jj = e - tl * 36;
        const unsigned char* srow = &S2[tl * 256];
        float acc = 0.f;
        for (int k = 0; k < 256; k += 4) {
            uchar4 q = *(const uchar4*)&srow[k];
            acc += (float)q.x * W3[(k + 0) * 36 + jj];
            acc += (float)q.y * W3[(k + 1) * 36 + jj];
            acc += (float)q.z * W3[(k + 2) * 36 + jj];
            acc += (float)q.w * W3[(k + 3) * 36 + jj];
        }
        G3[e] = acc;
    }
    __syncthreads();
    if (tid < 36) {
        int n = tid;
        float b = b3[n];
        float m = 0.f, s = 0.f;
        int cnt = 0;
        for (int t = gs; t < t0 + 50; ++t) {
            float v = G3[(t - gs) * 36 + n] + b;
            m = m * 0.2f * (1.f - s) + v;
            s = (m > 0.5f) ? 1.f : 0.f;
            if (t >= t0) cnt += (s != 0.f) ? 1 : 0;
        }
        atomicAdd(&out[n], (float)cnt * 0.0005f);
    }
}

extern "C" void kernel_launch(void* const* d_in, const int* in_sizes, int n_in,
                              void* d_out, int out_size, void* d_ws, size_t ws_size,
                              hipStream_t stream) {
    const float* x  = (const float*)d_in[0];
    const int*   ei = (const int*)d_in[1];
    const float* Wc = (const float*)d_in[2];
    const float* bc = (const float*)d_in[3];
    const float* W1 = (const float*)d_in[4];
    const float* b1 = (const float*)d_in[5];
    const float* W2 = (const float*)d_in[6];
    const float* b2 = (const float*)d_in[7];
    const float* W3 = (const float*)d_in[8];
    const float* b3 = (const float*)d_in[9];
    float* out = (float*)d_out;

    float* w = (float*)d_ws;
    float* F1p = w;                       w += (size_t)KS * FSP;   // 1,536,000 f
    float* G2  = w;                       w += (size_t)T * 256;    //   512,000 f
    unsigned char* FS = (unsigned char*)w;                         // 4,992,000 B

    hipMemsetAsync(out, 0, 36 * sizeof(float), stream);
    conv_scan<<<dim3(10, 40), 256, 0, stream>>>(x, ei, Wc, bc, FS);
    gemm1<<<dim3(63, 6), 256, 0, stream>>>(FS, W1, F1p);
    h1_gemm2<<<125, 256, 0, stream>>>(F1p, b1, W2, G2);
    tail<<<40, 256, 0, stream>>>(G2, b2, W3, b3, out);
}

// Round 6
// 291.192 us; speedup vs baseline: 3.4449x; 1.1234x over previous
//
#include <hip/hip_runtime.h>

#define T 2000
#define K1N 2496         // 39*64
#define K2 4992          // hi/lo duplicated K (bf16 shorts per W1t row)
#define KS 6             // gemm1 K-splits (partial buffers, no atomics)
#define KSP 832          // K2 per split
#define FSP (T * 128)    // elements per F1 partial

using short8 = __attribute__((ext_vector_type(8))) short;
using floatx4 = __attribute__((ext_vector_type(4))) float;

__device__ __forceinline__ unsigned bf16_rne(float v) {
    unsigned u = __float_as_uint(v);
    return (u + 0x7FFFu + ((u >> 16) & 1u)) >> 16;
}
__device__ __forceinline__ unsigned packhl(float w) {
    unsigned hi = bf16_rne(w);
    float r = w - __uint_as_float(hi << 16);   // exact
    unsigned lo = bf16_rne(r);
    return (hi & 0xFFFFu) | (lo << 16);
}

// ============ K1: A_hat + 3 hops (LDS ping-pong) + c1 scan -> FS; + W1 bf16 pack =====
// grid (10, 40): blockIdx.x = neuron group (256 neurons = 4 nodes), .y = 50-t chunk.
__global__ __launch_bounds__(256) void conv_scan(const float* __restrict__ x,
        const int* __restrict__ ei, const float* __restrict__ Wc,
        const float* __restrict__ bc, unsigned char* __restrict__ FS,
        const float* __restrict__ W1, unsigned* __restrict__ W1t) {
    __shared__ float ah[1560];      // A_hat [39][39], dinv at 1521..1559
    __shared__ float bufA[3900];    // [78 rows][50 t]
    __shared__ float bufB[3900];
    __shared__ float own[1600];     // [4 levels][8 local rows][50 t]
    int tid = threadIdx.x;
    int nb = blockIdx.x, ch = blockIdx.y;

    for (int u = tid; u < 1521; u += 256) ah[u] = 0.f;
    __syncthreads();
    if (tid < 156) atomicAdd(&ah[ei[156 + tid] * 39 + ei[tid]], 1.f);
    __syncthreads();
    if (tid < 39) {
        float d = 0.f;
        for (int u = 0; u < 39; ++u) d += ah[tid * 39 + u];
        ah[1521 + tid] = (d > 0.f) ? (1.f / sqrtf(d)) : 0.f;
    }
    __syncthreads();
    for (int u = tid; u < 1521; u += 256) {
        int i = u / 39, j = u - i * 39;
        ah[u] = (ah[1521 + i] * ah[u]) * ah[1521 + j];
    }
    __syncthreads();

    int t0 = ch * 50;
    int n = nb * 256 + tid;
    bool vn = n < K1N;
    int i0 = nb * 4;
    int iloc = (n >> 6) - i0;
    int j = n & 63;
    float wv[8], bias = 0.f;
    #pragma unroll
    for (int q = 0; q < 8; ++q) wv[q] = 0.f;
    if (vn) {
        #pragma unroll
        for (int q = 0; q < 8; ++q) wv[q] = Wc[q * 64 + j];
        bias = bc[j];
    }
    float m = 0.f, s = 0.f;
    for (int st = 0; st < 2; ++st) {         // st=0: warm sub-tile, st=1: output sub-tile
        int ts = t0 + (st - 1) * 50;
        if (ts < 0) continue;
        for (int e = tid; e < 3900; e += 256) {
            int r = e / 50, tt = e - r * 50;
            bufA[e] = x[r * T + ts + tt];
        }
        __syncthreads();
        for (int e = tid; e < 400; e += 256) {           // own level 0 (x)
            int lr = e / 50, tt = e - lr * 50;
            int gr = i0 * 2 + lr;
            own[e] = (gr < 78) ? bufA[gr * 50 + tt] : 0.f;
        }
        for (int e = tid; e < 3900; e += 256) {          // h1 = A_hat @ x
            int r = e / 50, tt = e - r * 50;
            int ii = r >> 1, c = r & 1;
            float acc = 0.f;
            #pragma unroll
            for (int mm = 0; mm < 39; ++mm) acc += ah[ii * 39 + mm] * bufA[(2 * mm + c) * 50 + tt];
            bufB[e] = acc;
        }
        __syncthreads();
        for (int e = tid; e < 400; e += 256) {           // own level 1
            int lr = e / 50, tt = e - lr * 50;
            int gr = i0 * 2 + lr;
            own[400 + e] = (gr < 78) ? bufB[gr * 50 + tt] : 0.f;
        }
        for (int e = tid; e < 3900; e += 256) {          // h2 = A_hat @ h1
            int r = e / 50, tt = e - r * 50;
            int ii = r >> 1, c = r & 1;
            float acc = 0.f;
            #pragma unroll
            for (int mm = 0; mm < 39; ++mm) acc += ah[ii * 39 + mm] * bufB[(2 * mm + c) * 50 + tt];
            bufA[e] = acc;
        }
        __syncthreads();
        for (int e = tid; e < 400; e += 256) {           // own level 2
            int lr = e / 50, tt = e - lr * 50;
            int gr = i0 * 2 + lr;
            own[800 + e] = (gr < 78) ? bufA[gr * 50 + tt] : 0.f;
        }
        for (int e = tid; e < 400; e += 256) {           // own level 3: h3 rows (own nodes)
            int lr = e / 50, tt = e - lr * 50;
            int gi = i0 + (lr >> 1), c = lr & 1;
            float acc = 0.f;
            if (gi < 39) {
                #pragma unroll
                for (int mm = 0; mm < 39; ++mm) acc += ah[gi * 39 + mm] * bufA[(2 * mm + c) * 50 + tt];
            }
            own[1200 + e] = acc;
        }
        __syncthreads();
        if (vn) {
            int ro = iloc * 2;
            for (int tt = 0; tt < 50; ++tt) {
                float acc = 0.f;
                #pragma unroll
                for (int lv = 0; lv < 4; ++lv) {
                    acc += wv[lv * 2 + 0] * own[lv * 400 + (ro + 0) * 50 + tt];
                    acc += wv[lv * 2 + 1] * own[lv * 400 + (ro + 1) * 50 + tt];
                }
                float v = acc + bias;
                m = m * 0.2f * (1.f - s) + v;
                s = (m > 0.5f) ? 1.f : 0.f;
                if (st == 1) FS[(ts + tt) * K1N + n] = (unsigned char)(s != 0.f);
            }
        }
        __syncthreads();
    }
    // ---- W1 -> bf16 hi/lo pack, strided across all 400 blocks (coalesced reads) ----
    {
        int bl = ch * 10 + nb;
        const int total = 128 * K1N;
        for (int f = bl * 256 + tid; f < total; f += 400 * 256) {
            int k = f >> 7, jj = f & 127;            // consecutive f -> consecutive W1
            W1t[jj * K1N + k] = packhl(W1[f]);
        }
    }
}

// ============ K2: gemm1 MFMA bf16 hi/lo (R2-verified), reads pre-packed W1t ==========
// grid (63, 6). F1p[ks][t][j] partial sums (no atomics).
__global__ __launch_bounds__(256) void gemm1(const unsigned char* __restrict__ FS,
        const short* __restrict__ W1t, float* __restrict__ F1p) {
    __shared__ short As[32 * 72];    // [m][k'] pad
    __shared__ short Ws[128 * 72];   // [j][k'] pad
    int tid = threadIdx.x;
    int t0 = blockIdx.x * 32;
    int ks = blockIdx.y;
    int lane = tid & 63, wvi = tid >> 6;
    int j0 = wvi * 32;
    int row = lane & 15, quad = lane >> 4;
    floatx4 a00 = {0.f, 0.f, 0.f, 0.f};
    floatx4 a01 = a00, a10 = a00, a11 = a00;
    int kb = ks * 416;
    int kb2 = ks * KSP;
    int sm = tid >> 3, sb4 = (tid & 7) * 4;
    for (int c = 0; c < 13; ++c) {
        unsigned u4 = 0;
        int gt = t0 + sm;
        if (gt < T) u4 = *(const unsigned*)&FS[gt * K1N + kb + c * 32 + sb4];
        uint4 dd;
        dd.x = (u4 & 0x000000FFu) ? 0x3F803F80u : 0u;
        dd.y = (u4 & 0x0000FF00u) ? 0x3F803F80u : 0u;
        dd.z = (u4 & 0x00FF0000u) ? 0x3F803F80u : 0u;
        dd.w = (u4 & 0xFF000000u) ? 0x3F803F80u : 0u;
        *(uint4*)&As[sm * 72 + sb4 * 2] = dd;
        #pragma unroll
        for (int u = 0; u < 4; ++u) {
            int aid = u * 256 + tid;
            int jj = aid >> 3;
            int ko = (aid & 7) * 8;
            short8 w = *(const short8*)&W1t[jj * K2 + kb2 + c * 64 + ko];
            *(short8*)&Ws[jj * 72 + ko] = w;
        }
        __syncthreads();
        #pragma unroll
        for (int sh = 0; sh < 2; ++sh) {
            int k0 = sh * 32 + quad * 8;
            short8 fa0 = *(const short8*)&As[row * 72 + k0];
            short8 fa1 = *(const short8*)&As[(row + 16) * 72 + k0];
            short8 fb0 = *(const short8*)&Ws[(j0 + row) * 72 + k0];
            short8 fb1 = *(const short8*)&Ws[(j0 + 16 + row) * 72 + k0];
            a00 = __builtin_amdgcn_mfma_f32_16x16x32_bf16(fa0, fb0, a00, 0, 0, 0);
            a01 = __builtin_amdgcn_mfma_f32_16x16x32_bf16(fa0, fb1, a01, 0, 0, 0);
            a10 = __builtin_amdgcn_mfma_f32_16x16x32_bf16(fa1, fb0, a10, 0, 0, 0);
            a11 = __builtin_amdgcn_mfma_f32_16x16x32_bf16(fa1, fb1, a11, 0, 0, 0);
        }
        __syncthreads();
    }
    float* outp = F1p + (size_t)ks * FSP;
    #pragma unroll
    for (int r = 0; r < 4; ++r) {
        int m0 = quad * 4 + r;
        int t = t0 + m0;
        if (t < T) { outp[t * 128 + j0 + row] = a00[r]; outp[t * 128 + j0 + 16 + row] = a01[r]; }
        int t2 = t0 + 16 + m0;
        if (t2 < T) { outp[t2 * 128 + j0 + row] = a10[r]; outp[t2 * 128 + j0 + 16 + row] = a11[r]; }
    }
}

// ============ K3: h1 scan (warm 20, per 16-t tile) + gemm2 -> G2 =====================
__global__ __launch_bounds__(256) void h1_gemm2(const float* __restrict__ F1p,
        const float* __restrict__ b1, const float* __restrict__ W2,
        float* __restrict__ G2) {
    __shared__ float AT[128 * 16];
    int tid = threadIdx.x;
    int t0 = blockIdx.x * 16;
    if (tid < 128) {
        int n = tid;
        int hs = t0 - 20; if (hs < 0) hs = 0;
        float b = b1[n];
        float m = 0.f, s = 0.f;
        const float* p0 = F1p + n;
        for (int t = hs; t < t0 + 16; ++t) {
            float v = 0.f;
            #pragma unroll
            for (int q = 0; q < KS; ++q) v += p0[(size_t)q * FSP + t * 128];
            v += b;
            m = m * 0.2f * (1.f - s) + v;
            s = (m > 0.5f) ? 1.f : 0.f;
            if (t >= t0) AT[n * 16 + (t - t0)] = s;
        }
    }
    __syncthreads();
    int j = tid;
    float acc[16] = {0.f};
    for (int k = 0; k < 128; ++k) {
        float w = W2[k * 256 + j];
        float4 q0 = *(const float4*)&AT[k * 16 + 0];
        float4 q1 = *(const float4*)&AT[k * 16 + 4];
        float4 q2 = *(const float4*)&AT[k * 16 + 8];
        float4 q3 = *(const float4*)&AT[k * 16 + 12];
        acc[0]  += q0.x * w; acc[1]  += q0.y * w; acc[2]  += q0.z * w; acc[3]  += q0.w * w;
        acc[4]  += q1.x * w; acc[5]  += q1.y * w; acc[6]  += q1.z * w; acc[7]  += q1.w * w;
        acc[8]  += q2.x * w; acc[9]  += q2.y * w; acc[10] += q2.z * w; acc[11] += q2.w * w;
        acc[12] += q3.x * w; acc[13] += q3.y * w; acc[14] += q3.z * w; acc[15] += q3.w * w;
    }
    #pragma unroll
    for (int tt = 0; tt < 16; ++tt) G2[(t0 + tt) * 256 + j] = acc[tt];
}

// ============ K4: h2 scan + gemm3 (W3 & S2 in LDS) + h3 scan + atomic out ============
// grid 80, L=25. h2 warm from t0-100; S2/G3 cover [t0-50, t0+25); h3 warm 50.
__global__ __launch_bounds__(256) void tail(const float* __restrict__ G2,
        const float* __restrict__ b2, const float* __restrict__ W3,
        const float* __restrict__ b3, float* __restrict__ out) {
    __shared__ unsigned char S2[76 * 256];   // 19.5 KB
    __shared__ float w3s[256 * 36];          // 36.9 KB, layout [k][j] == W3 linear
    __shared__ float G3[76 * 36];            // 10.7 KB
    int tid = threadIdx.x;
    int t0 = blockIdx.x * 25;
    int gs = t0 - 50; if (gs < 0) gs = 0;
    int hs = gs - 50; if (hs < 0) hs = 0;
    int L3 = t0 + 25 - gs;                   // <= 75
    // stage W3 (coalesced, once)
    for (int u = tid; u < 256 * 36; u += 256) w3s[u] = W3[u];
    // h2 scan: thread n = neuron n
    {
        int n = tid;
        float b = b2[n];
        float m = 0.f, s = 0.f;
        for (int t = hs; t < t0 + 25; ++t) {
            float v = G2[t * 256 + n] + b;
            m = m * 0.2f * (1.f - s) + v;
            s = (m > 0.5f) ? 1.f : 0.f;
            if (t >= gs) S2[(t - gs) * 256 + n] = (unsigned char)(s != 0.f);
        }
    }
    __syncthreads();
    // gemm3: thread owns (jj, 4 t-rows); W3 value reused across 4 rows
    {
        int nTG = (L3 + 3) >> 2;
        for (int e = tid; e < 36 * nTG; e += 256) {
            int jj = e % 36, tb = (e / 36) * 4;
            float ac0 = 0.f, ac1 = 0.f, ac2 = 0.f, ac3 = 0.f;
            bool v1 = tb + 1 < L3, v2 = tb + 2 < L3, v3 = tb + 3 < L3;
            const unsigned char* r0 = &S2[tb * 256];
            for (int k = 0; k < 256; k += 4) {
                float w0 = w3s[(k + 0) * 36 + jj];
                float w1 = w3s[(k + 1) * 36 + jj];
                float w2 = w3s[(k + 2) * 36 + jj];
                float w3v = w3s[(k + 3) * 36 + jj];
                uchar4 q0 = *(const uchar4*)&r0[k];
                ac0 += (float)q0.x * w0 + (float)q0.y * w1 + (float)q0.z * w2 + (float)q0.w * w3v;
                if (v1) {
                    uchar4 q = *(const uchar4*)&r0[256 + k];
                    ac1 += (float)q.x * w0 + (float)q.y * w1 + (float)q.z * w2 + (float)q.w * w3v;
                }
                if (v2) {
                    uchar4 q = *(const uchar4*)&r0[512 + k];
                    ac2 += (float)q.x * w0 + (float)q.y * w1 + (float)q.z * w2 + (float)q.w * w3v;
                }
                if (v3) {
                    uchar4 q = *(const uchar4*)&r0[768 + k];
                    ac3 += (float)q.x * w0 + (float)q.y * w1 + (float)q.z * w2 + (float)q.w * w3v;
                }
            }
            G3[tb * 36 + jj] = ac0;
            if (v1) G3[(tb + 1) * 36 + jj] = ac1;
            if (v2) G3[(tb + 2) * 36 + jj] = ac2;
            if (v3) G3[(tb + 3) * 36 + jj] = ac3;
        }
    }
    __syncthreads();
    if (tid < 36) {
        int n = tid;
        float b = b3[n];
        float m = 0.f, s = 0.f;
        int cnt = 0;
        for (int t = gs; t < t0 + 25; ++t) {
            float v = G3[(t - gs) * 36 + n] + b;
            m = m * 0.2f * (1.f - s) + v;
            s = (m > 0.5f) ? 1.f : 0.f;
            if (t >= t0) cnt += (s != 0.f) ? 1 : 0;
        }
        atomicAdd(&out[n], (float)cnt * 0.0005f);
    }
}

extern "C" void kernel_launch(void* const* d_in, const int* in_sizes, int n_in,
                              void* d_out, int out_size, void* d_ws, size_t ws_size,
                              hipStream_t stream) {
    const float* x  = (const float*)d_in[0];
    const int*   ei = (const int*)d_in[1];
    const float* Wc = (const float*)d_in[2];
    const float* bc = (const float*)d_in[3];
    const float* W1 = (const float*)d_in[4];
    const float* b1 = (const float*)d_in[5];
    const float* W2 = (const float*)d_in[6];
    const float* b2 = (const float*)d_in[7];
    const float* W3 = (const float*)d_in[8];
    const float* b3 = (const float*)d_in[9];
    float* out = (float*)d_out;

    float* w = (float*)d_ws;
    float* F1p = w;                       w += (size_t)KS * FSP;   // 1,536,000 f
    float* G2  = w;                       w += (size_t)T * 256;    //   512,000 f
    unsigned* W1t = (unsigned*)w;         w += 128 * K1N;          //   319,488 u32
    unsigned char* FS = (unsigned char*)w;                         // 4,992,000 B

    hipMemsetAsync(out, 0, 36 * sizeof(float), stream);
    conv_scan<<<dim3(10, 40), 256, 0, stream>>>(x, ei, Wc, bc, FS, W1, W1t);
    gemm1<<<dim3(63, 6), 256, 0, stream>>>(FS, (const short*)W1t, F1p);
    h1_gemm2<<<125, 256, 0, stream>>>(F1p, b1, W2, G2);
    tail<<<80, 256, 0, stream>>>(G2, b2, W3, b3, out);
}

// Round 7
// 170.781 us; speedup vs baseline: 5.8738x; 1.7051x over previous
//
#include <hip/hip_runtime.h>

#define T 2000
#define K1N 2496         // 39*64
#define K2 4992          // hi/lo duplicated K (bf16 shorts per W1t row)
#define TL 48            // conv_scan time tile
#define NCHB 42          // ceil(2000/48)

using short8 = __attribute__((ext_vector_type(8))) short;
using floatx4 = __attribute__((ext_vector_type(4))) float;

__device__ __forceinline__ unsigned bf16_rne(float v) {
    unsigned u = __float_as_uint(v);
    return (u + 0x7FFFu + ((u >> 16) & 1u)) >> 16;
}
__device__ __forceinline__ unsigned packhl(float w) {
    unsigned hi = bf16_rne(w);
    float r = w - __uint_as_float(hi << 16);   // exact
    unsigned lo = bf16_rne(r);
    return (hi & 0xFFFFu) | (lo << 16);
}

// ============ K1: A_hat + 3 hops (register-blocked) + c1 scan -> FS; W1 pack =========
// grid (10, 42). Exact per-output FMA order preserved (mm 0..38; q 0..7).
__global__ __launch_bounds__(256) void conv_scan(const float* __restrict__ x,
        const int* __restrict__ ei, const float* __restrict__ Wc,
        const float* __restrict__ bc, unsigned char* __restrict__ FS,
        const float* __restrict__ W1, unsigned* __restrict__ W1t,
        float* __restrict__ out) {
    __shared__ float ah[1560];          // A_hat [39][39] + dinv at 1521..1559
    __shared__ float bufA[78 * TL];     // 3744
    __shared__ float bufB[78 * TL];
    __shared__ float feat[4 * TL * 8];  // [iloc][tt][q]
    int tid = threadIdx.x;
    int nb = blockIdx.x, ch = blockIdx.y;
    int bl = ch * 10 + nb;

    if (bl == 0 && tid < 36) out[tid] = 0.f;   // replaces memset node (tail runs later)

    for (int u = tid; u < 1521; u += 256) ah[u] = 0.f;
    __syncthreads();
    if (tid < 156) atomicAdd(&ah[ei[156 + tid] * 39 + ei[tid]], 1.f);
    __syncthreads();
    if (tid < 39) {
        float d = 0.f;
        for (int u = 0; u < 39; ++u) d += ah[tid * 39 + u];
        ah[1521 + tid] = (d > 0.f) ? (1.f / sqrtf(d)) : 0.f;
    }
    __syncthreads();
    for (int u = tid; u < 1521; u += 256) {
        int i = u / 39, j = u - i * 39;
        ah[u] = (ah[1521 + i] * ah[u]) * ah[1521 + j];
    }
    __syncthreads();

    int t0 = ch * TL;
    int i0 = nb * 4;
    int iloc = tid >> 6, j = tid & 63;
    bool vn = (i0 + iloc) < 39;
    float wv[8], bias = 0.f;
    #pragma unroll
    for (int q = 0; q < 8; ++q) wv[q] = Wc[q * 64 + j];
    bias = bc[j];
    float m = 0.f, s = 0.f;

    for (int st = 0; st < 2; ++st) {          // st=0: warm subtile, st=1: output subtile
        int ts = t0 + (st - 1) * TL;
        if (ts < 0) continue;
        // ---- stage x (guard t >= T) ----
        for (int e = tid; e < 78 * TL; e += 256) {
            int r = e / TL, tt = e - (e / TL) * TL;
            int t = ts + tt;
            bufA[e] = (t < T) ? x[r * T + t] : 0.f;
        }
        __syncthreads();
        // ---- extract lv0 (x) + h1 = A_hat @ x ----
        for (int e = tid; e < 384; e += 256) {
            int lr = e / TL, tt = e - (e / TL) * TL;
            int gr = i0 * 2 + lr;
            float v = (gr < 78) ? bufA[gr * TL + tt] : 0.f;
            feat[(((lr >> 1) * TL) + tt) * 8 + (lr & 1)] = v;
        }
        for (int e = tid; e < 468; e += 256) {
            int r = e / 6, g = e - (e / 6) * 6;
            int ii = r >> 1, c = r & 1;
            float acc[8];
            #pragma unroll
            for (int u = 0; u < 8; ++u) acc[u] = 0.f;
            #pragma unroll 13
            for (int mm = 0; mm < 39; ++mm) {
                float a = ah[ii * 39 + mm];
                const float* xp = &bufA[(2 * mm + c) * TL + g * 8];
                float4 x0 = *(const float4*)xp;
                float4 x1 = *(const float4*)(xp + 4);
                acc[0] += a * x0.x; acc[1] += a * x0.y; acc[2] += a * x0.z; acc[3] += a * x0.w;
                acc[4] += a * x1.x; acc[5] += a * x1.y; acc[6] += a * x1.z; acc[7] += a * x1.w;
            }
            float* dp = &bufB[r * TL + g * 8];
            *(float4*)dp = *(float4*)&acc[0];
            *(float4*)(dp + 4) = *(float4*)&acc[4];
        }
        __syncthreads();
        // ---- extract lv1 + h2 = A_hat @ h1 ----
        for (int e = tid; e < 384; e += 256) {
            int lr = e / TL, tt = e - (e / TL) * TL;
            int gr = i0 * 2 + lr;
            float v = (gr < 78) ? bufB[gr * TL + tt] : 0.f;
            feat[(((lr >> 1) * TL) + tt) * 8 + 2 + (lr & 1)] = v;
        }
        for (int e = tid; e < 468; e += 256) {
            int r = e / 6, g = e - (e / 6) * 6;
            int ii = r >> 1, c = r & 1;
            float acc[8];
            #pragma unroll
            for (int u = 0; u < 8; ++u) acc[u] = 0.f;
            #pragma unroll 13
            for (int mm = 0; mm < 39; ++mm) {
                float a = ah[ii * 39 + mm];
                const float* xp = &bufB[(2 * mm + c) * TL + g * 8];
                float4 x0 = *(const float4*)xp;
                float4 x1 = *(const float4*)(xp + 4);
                acc[0] += a * x0.x; acc[1] += a * x0.y; acc[2] += a * x0.z; acc[3] += a * x0.w;
                acc[4] += a * x1.x; acc[5] += a * x1.y; acc[6] += a * x1.z; acc[7] += a * x1.w;
            }
            float* dp = &bufA[r * TL + g * 8];
            *(float4*)dp = *(float4*)&acc[0];
            *(float4*)(dp + 4) = *(float4*)&acc[4];
        }
        __syncthreads();
        // ---- extract lv2 + own-rows h3 -> feat ----
        for (int e = tid; e < 384; e += 256) {
            int lr = e / TL, tt = e - (e / TL) * TL;
            int gr = i0 * 2 + lr;
            float v = (gr < 78) ? bufA[gr * TL + tt] : 0.f;
            feat[(((lr >> 1) * TL) + tt) * 8 + 4 + (lr & 1)] = v;
        }
        for (int e = tid; e < 48; e += 256) {
            int lr = e / 6, g = e - (e / 6) * 6;
            int gi = i0 + (lr >> 1), c = lr & 1, il = lr >> 1;
            float acc[8];
            #pragma unroll
            for (int u = 0; u < 8; ++u) acc[u] = 0.f;
            if (gi < 39) {
                #pragma unroll 13
                for (int mm = 0; mm < 39; ++mm) {
                    float a = ah[gi * 39 + mm];
                    const float* xp = &bufA[(2 * mm + c) * TL + g * 8];
                    float4 x0 = *(const float4*)xp;
                    float4 x1 = *(const float4*)(xp + 4);
                    acc[0] += a * x0.x; acc[1] += a * x0.y; acc[2] += a * x0.z; acc[3] += a * x0.w;
                    acc[4] += a * x1.x; acc[5] += a * x1.y; acc[6] += a * x1.z; acc[7] += a * x1.w;
                }
            }
            #pragma unroll
            for (int u = 0; u < 8; ++u)
                feat[((il * TL) + g * 8 + u) * 8 + 6 + c] = acc[u];
        }
        __syncthreads();
        // ---- scan 48 steps (broadcast b128 feat reads) ----
        for (int tt = 0; tt < TL; ++tt) {
            const float4* fp = (const float4*)&feat[((iloc * TL) + tt) * 8];
            float4 f0 = fp[0], f1 = fp[1];
            float acc = 0.f;
            acc += wv[0] * f0.x; acc += wv[1] * f0.y; acc += wv[2] * f0.z; acc += wv[3] * f0.w;
            acc += wv[4] * f1.x; acc += wv[5] * f1.y; acc += wv[6] * f1.z; acc += wv[7] * f1.w;
            float v = acc + bias;
            m = m * 0.2f * (1.f - s) + v;
            s = (m > 0.5f) ? 1.f : 0.f;
            if (st == 1 && vn) {
                int t = ts + tt;
                if (t < T) FS[t * K1N + (nb * 256 + tid)] = (unsigned char)(s != 0.f);
            }
        }
        __syncthreads();
    }
    // ---- W1 -> bf16 hi/lo pack (coalesced, strided over 420 blocks) ----
    const int total = 128 * K1N;
    for (int f = bl * 256 + tid; f < total; f += 420 * 256) {
        int k = f >> 7, jj = f & 127;
        W1t[jj * K1N + k] = packhl(W1[f]);
    }
}

// ============ K2: gemm1 MFMA bf16 hi/lo, register-prefetched chunks ==================
// grid (63, 6). F1p layout [t][6][128] partial sums.
__global__ __launch_bounds__(256) void gemm1(const unsigned char* __restrict__ FS,
        const short* __restrict__ W1t, float* __restrict__ F1p) {
    __shared__ short As[32 * 72];
    __shared__ short Ws[128 * 72];
    int tid = threadIdx.x;
    int t0 = blockIdx.x * 32;
    int ks = blockIdx.y;
    int lane = tid & 63, wvi = tid >> 6;
    int j0 = wvi * 32;
    int row = lane & 15, quad = lane >> 4;
    floatx4 a00 = {0.f, 0.f, 0.f, 0.f};
    floatx4 a01 = a00, a10 = a00, a11 = a00;
    int kb = ks * 416, kb2 = ks * 832;
    int sm = tid >> 3, sb4 = (tid & 7) * 4;
    int gt = t0 + sm;
    int jjv[4], kov[4];
    #pragma unroll
    for (int u = 0; u < 4; ++u) {
        int aid = u * 256 + tid;
        jjv[u] = aid >> 3;
        kov[u] = (aid & 7) * 8;
    }
    unsigned u4 = 0;
    short8 wr0, wr1, wr2, wr3;
    if (gt < T) u4 = *(const unsigned*)&FS[gt * K1N + kb + sb4];
    wr0 = *(const short8*)&W1t[jjv[0] * K2 + kb2 + kov[0]];
    wr1 = *(const short8*)&W1t[jjv[1] * K2 + kb2 + kov[1]];
    wr2 = *(const short8*)&W1t[jjv[2] * K2 + kb2 + kov[2]];
    wr3 = *(const short8*)&W1t[jjv[3] * K2 + kb2 + kov[3]];
    for (int c = 0; c < 13; ++c) {
        uint4 dd;
        dd.x = (u4 & 0x000000FFu) ? 0x3F803F80u : 0u;
        dd.y = (u4 & 0x0000FF00u) ? 0x3F803F80u : 0u;
        dd.z = (u4 & 0x00FF0000u) ? 0x3F803F80u : 0u;
        dd.w = (u4 & 0xFF000000u) ? 0x3F803F80u : 0u;
        *(uint4*)&As[sm * 72 + sb4 * 2] = dd;
        *(short8*)&Ws[jjv[0] * 72 + kov[0]] = wr0;
        *(short8*)&Ws[jjv[1] * 72 + kov[1]] = wr1;
        *(short8*)&Ws[jjv[2] * 72 + kov[2]] = wr2;
        *(short8*)&Ws[jjv[3] * 72 + kov[3]] = wr3;
        __syncthreads();
        unsigned u4n = 0;
        short8 wn0, wn1, wn2, wn3;
        if (c < 12) {
            if (gt < T) u4n = *(const unsigned*)&FS[gt * K1N + kb + (c + 1) * 32 + sb4];
            wn0 = *(const short8*)&W1t[jjv[0] * K2 + kb2 + (c + 1) * 64 + kov[0]];
            wn1 = *(const short8*)&W1t[jjv[1] * K2 + kb2 + (c + 1) * 64 + kov[1]];
            wn2 = *(const short8*)&W1t[jjv[2] * K2 + kb2 + (c + 1) * 64 + kov[2]];
            wn3 = *(const short8*)&W1t[jjv[3] * K2 + kb2 + (c + 1) * 64 + kov[3]];
        }
        #pragma unroll
        for (int sh = 0; sh < 2; ++sh) {
            int k0 = sh * 32 + quad * 8;
            short8 fa0 = *(const short8*)&As[row * 72 + k0];
            short8 fa1 = *(const short8*)&As[(row + 16) * 72 + k0];
            short8 fb0 = *(const short8*)&Ws[(j0 + row) * 72 + k0];
            short8 fb1 = *(const short8*)&Ws[(j0 + 16 + row) * 72 + k0];
            a00 = __builtin_amdgcn_mfma_f32_16x16x32_bf16(fa0, fb0, a00, 0, 0, 0);
            a01 = __builtin_amdgcn_mfma_f32_16x16x32_bf16(fa0, fb1, a01, 0, 0, 0);
            a10 = __builtin_amdgcn_mfma_f32_16x16x32_bf16(fa1, fb0, a10, 0, 0, 0);
            a11 = __builtin_amdgcn_mfma_f32_16x16x32_bf16(fa1, fb1, a11, 0, 0, 0);
        }
        __syncthreads();
        if (c < 12) { u4 = u4n; wr0 = wn0; wr1 = wn1; wr2 = wn2; wr3 = wn3; }
    }
    #pragma unroll
    for (int r = 0; r < 4; ++r) {
        int m0 = quad * 4 + r;
        int t = t0 + m0;
        if (t < T) {
            F1p[t * 768 + ks * 128 + j0 + row] = a00[r];
            F1p[t * 768 + ks * 128 + j0 + 16 + row] = a01[r];
        }
        int t2 = t0 + 16 + m0;
        if (t2 < T) {
            F1p[t2 * 768 + ks * 128 + j0 + row] = a10[r];
            F1p[t2 * 768 + ks * 128 + j0 + 16 + row] = a11[r];
        }
    }
}

// ============ K3: h1 scan (warm 20, batch-4 prefetch) + gemm2 -> G2 ==================
__global__ __launch_bounds__(256) void h1_gemm2(const float* __restrict__ F1p,
        const float* __restrict__ b1, const float* __restrict__ W2,
        float* __restrict__ G2) {
    __shared__ float AT[128 * 16];
    int tid = threadIdx.x;
    int t0 = blockIdx.x * 16;
    if (tid < 128) {
        int n = tid;
        int hs = t0 - 20; if (hs < 0) hs = 0;
        float b = b1[n];
        float m = 0.f, s = 0.f;
        for (int tg = hs; tg < t0 + 16; tg += 4) {     // lengths 16/32/36: all %4==0
            float vb[4][6];
            #pragma unroll
            for (int u = 0; u < 4; ++u)
                #pragma unroll
                for (int q = 0; q < 6; ++q)
                    vb[u][q] = F1p[(tg + u) * 768 + q * 128 + n];
            #pragma unroll
            for (int u = 0; u < 4; ++u) {
                float v = 0.f;
                #pragma unroll
                for (int q = 0; q < 6; ++q) v += vb[u][q];
                v += b;
                m = m * 0.2f * (1.f - s) + v;
                s = (m > 0.5f) ? 1.f : 0.f;
                int t = tg + u;
                if (t >= t0) AT[n * 16 + (t - t0)] = s;
            }
        }
    }
    __syncthreads();
    int j = tid;
    float acc[16] = {0.f};
    #pragma unroll 4
    for (int k = 0; k < 128; ++k) {
        float w = W2[k * 256 + j];
        float4 q0 = *(const float4*)&AT[k * 16 + 0];
        float4 q1 = *(const float4*)&AT[k * 16 + 4];
        float4 q2 = *(const float4*)&AT[k * 16 + 8];
        float4 q3 = *(const float4*)&AT[k * 16 + 12];
        acc[0]  += q0.x * w; acc[1]  += q0.y * w; acc[2]  += q0.z * w; acc[3]  += q0.w * w;
        acc[4]  += q1.x * w; acc[5]  += q1.y * w; acc[6]  += q1.z * w; acc[7]  += q1.w * w;
        acc[8]  += q2.x * w; acc[9]  += q2.y * w; acc[10] += q2.z * w; acc[11] += q2.w * w;
        acc[12] += q3.x * w; acc[13] += q3.y * w; acc[14] += q3.z * w; acc[15] += q3.w * w;
    }
    #pragma unroll
    for (int tt = 0; tt < 16; ++tt) G2[(t0 + tt) * 256 + j] = acc[tt];
}

// ============ K4: h2 (batch-25 prefetch) + gemm3 (transposed W3 LDS) + h3 + out ======
// grid 80, L=25. h2 warm from t0-100; S2/G3 cover [t0-50, t0+25); h3 warm 50.
__global__ __launch_bounds__(256) void tail(const float* __restrict__ G2,
        const float* __restrict__ b2, const float* __restrict__ W3,
        const float* __restrict__ b3, float* __restrict__ out) {
    __shared__ float w3t[36 * 260];          // [jj][k] pad 260
    __shared__ unsigned char S2[76 * 260];   // [t][n] pad 260
    __shared__ float G3[76 * 36];
    int tid = threadIdx.x;
    int t0 = blockIdx.x * 25;
    int gs = t0 - 50; if (gs < 0) gs = 0;
    int hs = gs - 50; if (hs < 0) hs = 0;
    int L3 = t0 + 25 - gs;                   // 25..75
    // stage W3 transposed (coalesced global float4 reads)
    #pragma unroll
    for (int u = 0; u < 9; ++u) {
        int f = u * 1024 + tid * 4;
        float4 wq = *(const float4*)&W3[f];
        int k0 = f / 36, j0 = f - k0 * 36;
        float wv[4] = {wq.x, wq.y, wq.z, wq.w};
        #pragma unroll
        for (int q = 0; q < 4; ++q) {
            int k = (j0 + q >= 36) ? k0 + 1 : k0;
            int jj = (j0 + q >= 36) ? (j0 + q - 36) : (j0 + q);
            w3t[jj * 260 + k] = wv[q];
        }
    }
    // h2 scan with batch-25 prefetch (range lengths are multiples of 25)
    {
        int n = tid;
        float b = b2[n];
        float m = 0.f, s = 0.f;
        for (int base = hs; base < t0 + 25; base += 25) {
            float vb[25];
            #pragma unroll
            for (int u = 0; u < 25; ++u) vb[u] = G2[(base + u) * 256 + n];
            #pragma unroll
            for (int u = 0; u < 25; ++u) {
                float v = vb[u] + b;
                m = m * 0.2f * (1.f - s) + v;
                s = (m > 0.5f) ? 1.f : 0.f;
                int t = base + u;
                if (t >= gs) S2[(t - gs) * 260 + n] = (unsigned char)(s != 0.f);
            }
        }
    }
    __syncthreads();
    // gemm3: jj-major lanes (w3t reads broadcast); thread owns (jj, 4 t-rows)
    for (int e = tid; e < 36 * 19; e += 256) {
        int jj = e / 19, g = e - (e / 19) * 19;
        int tb = g * 4;
        if (tb >= L3) continue;
        float ac0 = 0.f, ac1 = 0.f, ac2 = 0.f, ac3 = 0.f;
        const unsigned char* r0 = &S2[tb * 260];
        for (int k = 0; k < 256; k += 4) {
            float4 w = *(const float4*)&w3t[jj * 260 + k];
            uchar4 q0 = *(const uchar4*)&r0[k];
            uchar4 q1 = *(const uchar4*)&r0[260 + k];
            uchar4 q2 = *(const uchar4*)&r0[520 + k];
            uchar4 q3 = *(const uchar4*)&r0[780 + k];
            ac0 += (float)q0.x * w.x + (float)q0.y * w.y + (float)q0.z * w.z + (float)q0.w * w.w;
            ac1 += (float)q1.x * w.x + (float)q1.y * w.y + (float)q1.z * w.z + (float)q1.w * w.w;
            ac2 += (float)q2.x * w.x + (float)q2.y * w.y + (float)q2.z * w.z + (float)q2.w * w.w;
            ac3 += (float)q3.x * w.x + (float)q3.y * w.y + (float)q3.z * w.z + (float)q3.w * w.w;
        }
        G3[tb * 36 + jj] = ac0;
        if (tb + 1 < L3) G3[(tb + 1) * 36 + jj] = ac1;
        if (tb + 2 < L3) G3[(tb + 2) * 36 + jj] = ac2;
        if (tb + 3 < L3) G3[(tb + 3) * 36 + jj] = ac3;
    }
    __syncthreads();
    if (tid < 36) {
        int n = tid;
        float b = b3[n];
        float m = 0.f, s = 0.f;
        int cnt = 0;
        for (int t = gs; t < t0 + 25; ++t) {
            float v = G3[(t - gs) * 36 + n] + b;
            m = m * 0.2f * (1.f - s) + v;
            s = (m > 0.5f) ? 1.f : 0.f;
            if (t >= t0) cnt += (s != 0.f) ? 1 : 0;
        }
        atomicAdd(&out[n], (float)cnt * 0.0005f);
    }
}

extern "C" void kernel_launch(void* const* d_in, const int* in_sizes, int n_in,
                              void* d_out, int out_size, void* d_ws, size_t ws_size,
                              hipStream_t stream) {
    const float* x  = (const float*)d_in[0];
    const int*   ei = (const int*)d_in[1];
    const float* Wc = (const float*)d_in[2];
    const float* bc = (const float*)d_in[3];
    const float* W1 = (const float*)d_in[4];
    const float* b1 = (const float*)d_in[5];
    const float* W2 = (const float*)d_in[6];
    const float* b2 = (const float*)d_in[7];
    const float* W3 = (const float*)d_in[8];
    const float* b3 = (const float*)d_in[9];
    float* out = (float*)d_out;

    float* w = (float*)d_ws;
    float* F1p = w;                       w += (size_t)T * 768;    // 1,536,000 f [t][6][128]
    float* G2  = w;                       w += (size_t)T * 256;    //   512,000 f
    unsigned* W1t = (unsigned*)w;         w += 128 * K1N;          //   319,488 u32
    unsigned char* FS = (unsigned char*)w;                         // 4,992,000 B

    conv_scan<<<dim3(10, NCHB), 256, 0, stream>>>(x, ei, Wc, bc, FS, W1, W1t, out);
    gemm1<<<dim3(63, 6), 256, 0, stream>>>(FS, (const short*)W1t, F1p);
    h1_gemm2<<<125, 256, 0, stream>>>(F1p, b1, W2, G2);
    tail<<<80, 256, 0, stream>>>(G2, b2, W3, b3, out);
}

// Round 8
// 161.235 us; speedup vs baseline: 6.2216x; 1.0592x over previous
//
#include <hip/hip_runtime.h>

#define T 2000
#define K1N 2496         // 39*64
#define K2 4992          // hi/lo duplicated K (bf16 shorts per W1t row)
#define TL 48            // conv_scan time tile
#define NCHB 42          // ceil(2000/48)
#define MAXNZ 24         // per-row nonzero cap (Poisson(4): P(>=24) ~ 1e-14)

using short8 = __attribute__((ext_vector_type(8))) short;
using floatx4 = __attribute__((ext_vector_type(4))) float;

__device__ __forceinline__ unsigned bf16_rne(float v) {
    unsigned u = __float_as_uint(v);
    return (u + 0x7FFFu + ((u >> 16) & 1u)) >> 16;
}
__device__ __forceinline__ unsigned packhl(float w) {
    unsigned hi = bf16_rne(w);
    float r = w - __uint_as_float(hi << 16);   // exact
    unsigned lo = bf16_rne(r);
    return (hi & 0xFFFFu) | (lo << 16);
}

// ============ K1: A_hat (sparse rows) + 3 hops + c1 scan -> FS; W1 pack ==============
// grid (10, 42). Bit-exact vs dense: zero terms skipped (acc+0*x==acc), nonzeros
// accumulated in ascending-m order, per-output FMA order otherwise unchanged.
__global__ __launch_bounds__(256) void conv_scan(const float* __restrict__ x,
        const int* __restrict__ ei, const float* __restrict__ Wc,
        const float* __restrict__ bc, unsigned char* __restrict__ FS,
        const float* __restrict__ W1, unsigned* __restrict__ W1t,
        float* __restrict__ out) {
    __shared__ float ah[1560];          // dense A_hat build scratch + dinv
    __shared__ float2 alist[39 * MAXNZ];// [i][e] = {a_im, asfloat((2m)*TL*4)}
    __shared__ int nnzr[40];
    __shared__ float bufA[78 * TL];
    __shared__ float bufB[78 * TL];
    __shared__ float feat[4 * TL * 8];  // [iloc][tt][q]
    int tid = threadIdx.x;
    int nb = blockIdx.x, ch = blockIdx.y;
    int bl = ch * 10 + nb;

    if (bl == 0 && tid < 36) out[tid] = 0.f;   // replaces memset node (tail runs later)

    for (int u = tid; u < 1521; u += 256) ah[u] = 0.f;
    __syncthreads();
    if (tid < 156) atomicAdd(&ah[ei[156 + tid] * 39 + ei[tid]], 1.f);
    __syncthreads();
    if (tid < 39) {
        float d = 0.f;
        for (int u = 0; u < 39; ++u) d += ah[tid * 39 + u];
        ah[1521 + tid] = (d > 0.f) ? (1.f / sqrtf(d)) : 0.f;
    }
    __syncthreads();
    for (int u = tid; u < 1521; u += 256) {
        int i = u / 39, j = u - i * 39;
        ah[u] = (ah[1521 + i] * ah[u]) * ah[1521 + j];
    }
    __syncthreads();
    // build sparse row lists (ascending m)
    if (tid < 39) {
        int cnt = 0;
        for (int m = 0; m < 39; ++m) {
            float v = ah[tid * 39 + m];
            if (v != 0.f && cnt < MAXNZ) {
                alist[tid * MAXNZ + cnt] = make_float2(v, __int_as_float((2 * m) * TL * 4));
                ++cnt;
            }
        }
        nnzr[tid] = cnt;
    }
    __syncthreads();

    int t0 = ch * TL;
    int i0 = nb * 4;
    int iloc = tid >> 6, j = tid & 63;
    bool vn = (i0 + iloc) < 39;
    float wv[8], bias;
    #pragma unroll
    for (int q = 0; q < 8; ++q) wv[q] = Wc[q * 64 + j];
    bias = bc[j];
    float m = 0.f, s = 0.f;

    for (int st = 0; st < 2; ++st) {          // st=0: warm subtile, st=1: output subtile
        int ts = t0 + (st - 1) * TL;
        if (ts < 0) continue;
        for (int e = tid; e < 78 * TL; e += 256) {
            int r = e / TL, tt = e - (e / TL) * TL;
            int t = ts + tt;
            bufA[e] = (t < T) ? x[r * T + t] : 0.f;
        }
        __syncthreads();
        // ---- lv0 extract + h1 = A_hat @ x (sparse) ----
        for (int e = tid; e < 384; e += 256) {
            int lr = e / TL, tt = e - (e / TL) * TL;
            int gr = i0 * 2 + lr;
            float v = (gr < 78) ? bufA[gr * TL + tt] : 0.f;
            feat[(((lr >> 1) * TL) + tt) * 8 + (lr & 1)] = v;
        }
        for (int e = tid; e < 468; e += 256) {
            int r = e / 6, g = e - (e / 6) * 6;
            int ii = r >> 1, c = r & 1;
            float acc[8];
            #pragma unroll
            for (int u = 0; u < 8; ++u) acc[u] = 0.f;
            int nz = nnzr[ii];
            const float2* lp = &alist[ii * MAXNZ];
            int cg = c * (TL * 4) + g * 32;
            for (int q = 0; q < nz; ++q) {
                float2 av = lp[q];
                const float* xp = (const float*)((const char*)bufA + (__float_as_int(av.y) + cg));
                float a = av.x;
                float4 x0 = *(const float4*)xp;
                float4 x1 = *(const float4*)(xp + 4);
                acc[0] += a * x0.x; acc[1] += a * x0.y; acc[2] += a * x0.z; acc[3] += a * x0.w;
                acc[4] += a * x1.x; acc[5] += a * x1.y; acc[6] += a * x1.z; acc[7] += a * x1.w;
            }
            float* dp = &bufB[r * TL + g * 8];
            *(float4*)dp = *(float4*)&acc[0];
            *(float4*)(dp + 4) = *(float4*)&acc[4];
        }
        __syncthreads();
        // ---- lv1 extract + h2 = A_hat @ h1 (sparse) ----
        for (int e = tid; e < 384; e += 256) {
            int lr = e / TL, tt = e - (e / TL) * TL;
            int gr = i0 * 2 + lr;
            float v = (gr < 78) ? bufB[gr * TL + tt] : 0.f;
            feat[(((lr >> 1) * TL) + tt) * 8 + 2 + (lr & 1)] = v;
        }
        for (int e = tid; e < 468; e += 256) {
            int r = e / 6, g = e - (e / 6) * 6;
            int ii = r >> 1, c = r & 1;
            float acc[8];
            #pragma unroll
            for (int u = 0; u < 8; ++u) acc[u] = 0.f;
            int nz = nnzr[ii];
            const float2* lp = &alist[ii * MAXNZ];
            int cg = c * (TL * 4) + g * 32;
            for (int q = 0; q < nz; ++q) {
                float2 av = lp[q];
                const float* xp = (const float*)((const char*)bufB + (__float_as_int(av.y) + cg));
                float a = av.x;
                float4 x0 = *(const float4*)xp;
                float4 x1 = *(const float4*)(xp + 4);
                acc[0] += a * x0.x; acc[1] += a * x0.y; acc[2] += a * x0.z; acc[3] += a * x0.w;
                acc[4] += a * x1.x; acc[5] += a * x1.y; acc[6] += a * x1.z; acc[7] += a * x1.w;
            }
            float* dp = &bufA[r * TL + g * 8];
            *(float4*)dp = *(float4*)&acc[0];
            *(float4*)(dp + 4) = *(float4*)&acc[4];
        }
        __syncthreads();
        // ---- lv2 extract + own-rows h3 (sparse) -> feat ----
        for (int e = tid; e < 384; e += 256) {
            int lr = e / TL, tt = e - (e / TL) * TL;
            int gr = i0 * 2 + lr;
            float v = (gr < 78) ? bufA[gr * TL + tt] : 0.f;
            feat[(((lr >> 1) * TL) + tt) * 8 + 4 + (lr & 1)] = v;
        }
        for (int e = tid; e < 48; e += 256) {
            int lr = e / 6, g = e - (e / 6) * 6;
            int gi = i0 + (lr >> 1), c = lr & 1, il = lr >> 1;
            float acc[8];
            #pragma unroll
            for (int u = 0; u < 8; ++u) acc[u] = 0.f;
            if (gi < 39) {
                int nz = nnzr[gi];
                const float2* lp = &alist[gi * MAXNZ];
                int cg = c * (TL * 4) + g * 32;
                for (int q = 0; q < nz; ++q) {
                    float2 av = lp[q];
                    const float* xp = (const float*)((const char*)bufA + (__float_as_int(av.y) + cg));
                    float a = av.x;
                    float4 x0 = *(const float4*)xp;
                    float4 x1 = *(const float4*)(xp + 4);
                    acc[0] += a * x0.x; acc[1] += a * x0.y; acc[2] += a * x0.z; acc[3] += a * x0.w;
                    acc[4] += a * x1.x; acc[5] += a * x1.y; acc[6] += a * x1.z; acc[7] += a * x1.w;
                }
            }
            #pragma unroll
            for (int u = 0; u < 8; ++u)
                feat[((il * TL) + g * 8 + u) * 8 + 6 + c] = acc[u];
        }
        __syncthreads();
        // ---- scan 48 steps (broadcast b128 feat reads) ----
        for (int tt = 0; tt < TL; ++tt) {
            const float4* fp = (const float4*)&feat[((iloc * TL) + tt) * 8];
            float4 f0 = fp[0], f1 = fp[1];
            float acc = 0.f;
            acc += wv[0] * f0.x; acc += wv[1] * f0.y; acc += wv[2] * f0.z; acc += wv[3] * f0.w;
            acc += wv[4] * f1.x; acc += wv[5] * f1.y; acc += wv[6] * f1.z; acc += wv[7] * f1.w;
            float v = acc + bias;
            m = m * 0.2f * (1.f - s) + v;
            s = (m > 0.5f) ? 1.f : 0.f;
            if (st == 1 && vn) {
                int t = ts + tt;
                if (t < T) FS[t * K1N + (nb * 256 + tid)] = (unsigned char)(s != 0.f);
            }
        }
        __syncthreads();
    }
    // ---- W1 -> bf16 hi/lo pack (coalesced, strided over 420 blocks) ----
    const int total = 128 * K1N;
    for (int f = bl * 256 + tid; f < total; f += 420 * 256) {
        int k = f >> 7, jj = f & 127;
        W1t[jj * K1N + k] = packhl(W1[f]);
    }
}

// ============ K2: gemm1 MFMA bf16 hi/lo, register-prefetched chunks ==================
// grid (63, 6). F1p layout [t][6][128] partial sums.
__global__ __launch_bounds__(256) void gemm1(const unsigned char* __restrict__ FS,
        const short* __restrict__ W1t, float* __restrict__ F1p) {
    __shared__ short As[32 * 72];
    __shared__ short Ws[128 * 72];
    int tid = threadIdx.x;
    int t0 = blockIdx.x * 32;
    int ks = blockIdx.y;
    int lane = tid & 63, wvi = tid >> 6;
    int j0 = wvi * 32;
    int row = lane & 15, quad = lane >> 4;
    floatx4 a00 = {0.f, 0.f, 0.f, 0.f};
    floatx4 a01 = a00, a10 = a00, a11 = a00;
    int kb = ks * 416, kb2 = ks * 832;
    int sm = tid >> 3, sb4 = (tid & 7) * 4;
    int gt = t0 + sm;
    int jjv[4], kov[4];
    #pragma unroll
    for (int u = 0; u < 4; ++u) {
        int aid = u * 256 + tid;
        jjv[u] = aid >> 3;
        kov[u] = (aid & 7) * 8;
    }
    unsigned u4 = 0;
    short8 wr0, wr1, wr2, wr3;
    if (gt < T) u4 = *(const unsigned*)&FS[gt * K1N + kb + sb4];
    wr0 = *(const short8*)&W1t[jjv[0] * K2 + kb2 + kov[0]];
    wr1 = *(const short8*)&W1t[jjv[1] * K2 + kb2 + kov[1]];
    wr2 = *(const short8*)&W1t[jjv[2] * K2 + kb2 + kov[2]];
    wr3 = *(const short8*)&W1t[jjv[3] * K2 + kb2 + kov[3]];
    for (int c = 0; c < 13; ++c) {
        uint4 dd;
        dd.x = (u4 & 0x000000FFu) ? 0x3F803F80u : 0u;
        dd.y = (u4 & 0x0000FF00u) ? 0x3F803F80u : 0u;
        dd.z = (u4 & 0x00FF0000u) ? 0x3F803F80u : 0u;
        dd.w = (u4 & 0xFF000000u) ? 0x3F803F80u : 0u;
        *(uint4*)&As[sm * 72 + sb4 * 2] = dd;
        *(short8*)&Ws[jjv[0] * 72 + kov[0]] = wr0;
        *(short8*)&Ws[jjv[1] * 72 + kov[1]] = wr1;
        *(short8*)&Ws[jjv[2] * 72 + kov[2]] = wr2;
        *(short8*)&Ws[jjv[3] * 72 + kov[3]] = wr3;
        __syncthreads();
        unsigned u4n = 0;
        short8 wn0, wn1, wn2, wn3;
        if (c < 12) {
            if (gt < T) u4n = *(const unsigned*)&FS[gt * K1N + kb + (c + 1) * 32 + sb4];
            wn0 = *(const short8*)&W1t[jjv[0] * K2 + kb2 + (c + 1) * 64 + kov[0]];
            wn1 = *(const short8*)&W1t[jjv[1] * K2 + kb2 + (c + 1) * 64 + kov[1]];
            wn2 = *(const short8*)&W1t[jjv[2] * K2 + kb2 + (c + 1) * 64 + kov[2]];
            wn3 = *(const short8*)&W1t[jjv[3] * K2 + kb2 + (c + 1) * 64 + kov[3]];
        }
        #pragma unroll
        for (int sh = 0; sh < 2; ++sh) {
            int k0 = sh * 32 + quad * 8;
            short8 fa0 = *(const short8*)&As[row * 72 + k0];
            short8 fa1 = *(const short8*)&As[(row + 16) * 72 + k0];
            short8 fb0 = *(const short8*)&Ws[(j0 + row) * 72 + k0];
            short8 fb1 = *(const short8*)&Ws[(j0 + 16 + row) * 72 + k0];
            a00 = __builtin_amdgcn_mfma_f32_16x16x32_bf16(fa0, fb0, a00, 0, 0, 0);
            a01 = __builtin_amdgcn_mfma_f32_16x16x32_bf16(fa0, fb1, a01, 0, 0, 0);
            a10 = __builtin_amdgcn_mfma_f32_16x16x32_bf16(fa1, fb0, a10, 0, 0, 0);
            a11 = __builtin_amdgcn_mfma_f32_16x16x32_bf16(fa1, fb1, a11, 0, 0, 0);
        }
        __syncthreads();
        if (c < 12) { u4 = u4n; wr0 = wn0; wr1 = wn1; wr2 = wn2; wr3 = wn3; }
    }
    #pragma unroll
    for (int r = 0; r < 4; ++r) {
        int m0 = quad * 4 + r;
        int t = t0 + m0;
        if (t < T) {
            F1p[t * 768 + ks * 128 + j0 + row] = a00[r];
            F1p[t * 768 + ks * 128 + j0 + 16 + row] = a01[r];
        }
        int t2 = t0 + 16 + m0;
        if (t2 < T) {
            F1p[t2 * 768 + ks * 128 + j0 + row] = a10[r];
            F1p[t2 * 768 + ks * 128 + j0 + 16 + row] = a11[r];
        }
    }
}

// ============ K3: h1 scan (warm 20) + gemm2, t-tile 8, grid 250 ======================
__global__ __launch_bounds__(256) void h1_gemm2(const float* __restrict__ F1p,
        const float* __restrict__ b1, const float* __restrict__ W2,
        float* __restrict__ G2) {
    __shared__ float AT[128 * 8];
    int tid = threadIdx.x;
    int t0 = blockIdx.x * 8;
    if (tid < 128) {
        int n = tid;
        int hs = t0 - 20; if (hs < 0) hs = 0;
        float b = b1[n];
        float m = 0.f, s = 0.f;
        for (int tg = hs; tg < t0 + 8; tg += 4) {     // lengths 8/28: both %4==0
            float vb[4][6];
            #pragma unroll
            for (int u = 0; u < 4; ++u)
                #pragma unroll
                for (int q = 0; q < 6; ++q)
                    vb[u][q] = F1p[(tg + u) * 768 + q * 128 + n];
            #pragma unroll
            for (int u = 0; u < 4; ++u) {
                float v = 0.f;
                #pragma unroll
                for (int q = 0; q < 6; ++q) v += vb[u][q];
                v += b;
                m = m * 0.2f * (1.f - s) + v;
                s = (m > 0.5f) ? 1.f : 0.f;
                int t = tg + u;
                if (t >= t0) AT[n * 8 + (t - t0)] = s;
            }
        }
    }
    __syncthreads();
    int j = tid;
    float acc[8] = {0.f};
    #pragma unroll 4
    for (int k = 0; k < 128; ++k) {
        float w = W2[k * 256 + j];
        float4 q0 = *(const float4*)&AT[k * 8 + 0];
        float4 q1 = *(const float4*)&AT[k * 8 + 4];
        acc[0] += q0.x * w; acc[1] += q0.y * w; acc[2] += q0.z * w; acc[3] += q0.w * w;
        acc[4] += q1.x * w; acc[5] += q1.y * w; acc[6] += q1.z * w; acc[7] += q1.w * w;
    }
    #pragma unroll
    for (int tt = 0; tt < 8; ++tt) G2[(t0 + tt) * 256 + j] = acc[tt];
}

// ============ K4: h2 (batch-25 prefetch) + gemm3 (transposed W3 LDS) + h3 + out ======
__global__ __launch_bounds__(256) void tail(const float* __restrict__ G2,
        const float* __restrict__ b2, const float* __restrict__ W3,
        const float* __restrict__ b3, float* __restrict__ out) {
    __shared__ float w3t[36 * 260];          // [jj][k] pad 260
    __shared__ unsigned char S2[76 * 260];   // [t][n] pad 260
    __shared__ float G3[76 * 36];
    int tid = threadIdx.x;
    int t0 = blockIdx.x * 25;
    int gs = t0 - 50; if (gs < 0) gs = 0;
    int hs = gs - 50; if (hs < 0) hs = 0;
    int L3 = t0 + 25 - gs;                   // 25..75
    #pragma unroll
    for (int u = 0; u < 9; ++u) {
        int f = u * 1024 + tid * 4;
        float4 wq = *(const float4*)&W3[f];
        int k0 = f / 36, j0 = f - k0 * 36;
        float wv[4] = {wq.x, wq.y, wq.z, wq.w};
        #pragma unroll
        for (int q = 0; q < 4; ++q) {
            int k = (j0 + q >= 36) ? k0 + 1 : k0;
            int jj = (j0 + q >= 36) ? (j0 + q - 36) : (j0 + q);
            w3t[jj * 260 + k] = wv[q];
        }
    }
    {
        int n = tid;
        float b = b2[n];
        float m = 0.f, s = 0.f;
        for (int base = hs; base < t0 + 25; base += 25) {
            float vb[25];
            #pragma unroll
            for (int u = 0; u < 25; ++u) vb[u] = G2[(base + u) * 256 + n];
            #pragma unroll
            for (int u = 0; u < 25; ++u) {
                float v = vb[u] + b;
                m = m * 0.2f * (1.f - s) + v;
                s = (m > 0.5f) ? 1.f : 0.f;
                int t = base + u;
                if (t >= gs) S2[(t - gs) * 260 + n] = (unsigned char)(s != 0.f);
            }
        }
    }
    __syncthreads();
    for (int e = tid; e < 36 * 19; e += 256) {
        int jj = e / 19, g = e - (e / 19) * 19;
        int tb = g * 4;
        if (tb >= L3) continue;
        float ac0 = 0.f, ac1 = 0.f, ac2 = 0.f, ac3 = 0.f;
        const unsigned char* r0 = &S2[tb * 260];
        for (int k = 0; k < 256; k += 4) {
            float4 w = *(const float4*)&w3t[jj * 260 + k];
            uchar4 q0 = *(const uchar4*)&r0[k];
            uchar4 q1 = *(const uchar4*)&r0[260 + k];
            uchar4 q2 = *(const uchar4*)&r0[520 + k];
            uchar4 q3 = *(const uchar4*)&r0[780 + k];
            ac0 += (float)q0.x * w.x + (float)q0.y * w.y + (float)q0.z * w.z + (float)q0.w * w.w;
            ac1 += (float)q1.x * w.x + (float)q1.y * w.y + (float)q1.z * w.z + (float)q1.w * w.w;
            ac2 += (float)q2.x * w.x + (float)q2.y * w.y + (float)q2.z * w.z + (float)q2.w * w.w;
            ac3 += (float)q3.x * w.x + (float)q3.y * w.y + (float)q3.z * w.z + (float)q3.w * w.w;
        }
        G3[tb * 36 + jj] = ac0;
        if (tb + 1 < L3) G3[(tb + 1) * 36 + jj] = ac1;
        if (tb + 2 < L3) G3[(tb + 2) * 36 + jj] = ac2;
        if (tb + 3 < L3) G3[(tb + 3) * 36 + jj] = ac3;
    }
    __syncthreads();
    if (tid < 36) {
        int n = tid;
        float b = b3[n];
        float m = 0.f, s = 0.f;
        int cnt = 0;
        for (int t = gs; t < t0 + 25; ++t) {
            float v = G3[(t - gs) * 36 + n] + b;
            m = m * 0.2f * (1.f - s) + v;
            s = (m > 0.5f) ? 1.f : 0.f;
            if (t >= t0) cnt += (s != 0.f) ? 1 : 0;
        }
        atomicAdd(&out[n], (float)cnt * 0.0005f);
    }
}

extern "C" void kernel_launch(void* const* d_in, const int* in_sizes, int n_in,
                              void* d_out, int out_size, void* d_ws, size_t ws_size,
                              hipStream_t stream) {
    const float* x  = (const float*)d_in[0];
    const int*   ei = (const int*)d_in[1];
    const float* Wc = (const float*)d_in[2];
    const float* bc = (const float*)d_in[3];
    const float* W1 = (const float*)d_in[4];
    const float* b1 = (const float*)d_in[5];
    const float* W2 = (const float*)d_in[6];
    const float* b2 = (const float*)d_in[7];
    const float* W3 = (const float*)d_in[8];
    const float* b3 = (const float*)d_in[9];
    float* out = (float*)d_out;

    float* w = (float*)d_ws;
    float* F1p = w;                       w += (size_t)T * 768;    // [t][6][128]
    float* G2  = w;                       w += (size_t)T * 256;
    unsigned* W1t = (unsigned*)w;         w += 128 * K1N;
    unsigned char* FS = (unsigned char*)w;                         // 4,992,000 B

    conv_scan<<<dim3(10, NCHB), 256, 0, stream>>>(x, ei, Wc, bc, FS, W1, W1t, out);
    gemm1<<<dim3(63, 6), 256, 0, stream>>>(FS, (const short*)W1t, F1p);
    h1_gemm2<<<250, 256, 0, stream>>>(F1p, b1, W2, G2);
    tail<<<80, 256, 0, stream>>>(G2, b2, W3, b3, out);
}